// Round 11
// baseline (151.209 us; speedup 1.0000x reference)
//
#include <hip/hip_runtime.h>
#include <hip/hip_bf16.h>
#include <math.h>

// Problem constants (B, Cin, Cmid, H, W) = (2, 256, 128, 112, 112), R=3
constexpr int B    = 2;
constexpr int CIN  = 256;
constexpr int CMID = 128;
constexpr int H    = 112;
constexpr int W    = 112;
constexpr int HW   = H * W;        // 12544
constexpr int NPIX = B * HW;       // 25088
constexpr int RAD  = 3;
constexpr int KS   = 7;
constexpr int DD   = 49;

typedef __attribute__((ext_vector_type(8))) short  short8;   // 8 bf16 (4 VGPR)
typedef __attribute__((ext_vector_type(4))) float  float4v;  // MFMA C/D

// RNE fp32-pair -> packed bf16x2 via v_cvt_pk_bf16_f32 (compiler-lowered)
__device__ __forceinline__ unsigned pkbf(float a, float b) {
    __hip_bfloat162 h = __float22bfloat162_rn(make_float2(a, b));
    union { __hip_bfloat162 h2; unsigned u; } c;
    c.h2 = h;
    return c.u;
}

// ---------------------------------------------------------------------------
// Kernel 0 (prep, tiny): Wq/Wk f32 -> bf16; Wv f32 -> padded f32 [49][52].
// Kept SEPARATE (R6 fold regressed: VGPR spill past the 128 cap in proj).
// ---------------------------------------------------------------------------
__global__ __launch_bounds__(256) void prep(
    const float* __restrict__ Wq, const float* __restrict__ Wk,
    const float* __restrict__ Wv,
    unsigned short* __restrict__ wqb, unsigned short* __restrict__ wkb,
    float* __restrict__ wvp)
{
    if (blockIdx.x < 64) {
        const int i  = blockIdx.x * 256 + threadIdx.x;   // float4 index
        const int n4 = (CMID * CIN) / 4;                 // 8192 per matrix
        const float4 v = (i < n4) ? ((const float4*)Wq)[i] : ((const float4*)Wk)[i - n4];
        uint2 r;
        r.x = pkbf(v.x, v.y);
        r.y = pkbf(v.z, v.w);
        if (i < n4) ((uint2*)wqb)[i] = r;
        else        ((uint2*)wkb)[i - n4] = r;
    } else {
        for (int idx = threadIdx.x; idx < DD * 52; idx += 256) {
            const int r = idx / 52, c = idx % 52;
            wvp[idx] = (c < DD) ? Wv[r * DD + c] : 0.f;
        }
    }
}

// ---------------------------------------------------------------------------
// Kernel 1: q = l2norm(Wq @ phi_cur), k = l2norm(Wk @ phi_rnd) -- ZERO-BARRIER.
// NEW this round: split work by PIXEL, not by och.  Wave w owns 16 pixels x
// all 128 och:
//  - wave stages ONLY its own 16 LDS rows and reads ONLY rows it wrote ->
//    NO __syncthreads (same-wave cross-lane LDS write->read is ordered by
//    lgkmcnt -- the C1->C2 pattern verified correct all session).
//  - l2norm fully in-wave (all 128 och in acc[8]) -> 2nd barrier + red gone.
//  - 16 independent waves/CU free-run: staging HBM latency and K-loop W-L2
//    latency hide via TLP instead of a phase-locked barrier drain.
//  - W streamed per-wave (64 KB bf16, L2-hot), 1-deep kc prefetch; aggregate
//    L2 demand ~8 TB/s << 34.5 TB/s ceiling.  Peak VGPR ~115 < 128.
// LDS: pixel-major bf16, PSTR=264, col XOR-swizzle ((row>>3)&3)<<3 (staging
// writes 2-way=free, frag b128 reads same verified residues).
// Staging keeps the R8 issue-early/write-late split (2 batches of 8 loads).
// ---------------------------------------------------------------------------
constexpr int PSTR = 264;           // shorts per pixel row in pt

__global__ __launch_bounds__(256, 4) void proj_mfma(
    const float* __restrict__ phi_cur, const float* __restrict__ phi_rnd,
    const unsigned short* __restrict__ wq_bf, const unsigned short* __restrict__ wk_bf,
    unsigned short* __restrict__ q_ws, unsigned short* __restrict__ k_ws)
{
    __shared__ unsigned short pt[64 * PSTR];  // 33,792 B  pixel-major bf16

    const int tid  = threadIdx.x;
    const int lane = tid & 63;
    const int wv   = __builtin_amdgcn_readfirstlane(tid >> 6);
    const int t    = blockIdx.y;                    // 0 -> q, 1 -> k

    const float* __restrict__ phi          = t ? phi_rnd : phi_cur;
    const unsigned short* __restrict__ Wbf = t ? wk_bf : wq_bf;
    unsigned short* __restrict__ outp      = t ? k_ws : q_ws;

    const int pgb = blockIdx.x * 64;                // 64-aligned, no b crossing
    const int b   = pgb / HW;
    const int pim = pgb % HW;
    const float* pbase = phi + (size_t)b * CIN * HW + pim;

    const int m = lane & 15, quad = lane >> 4;
    const int prow0 = wv * 16;                      // wave's 16 LDS rows

    // ---- stage wave's 16 pixels x 256 ch: 2 batches x {8 loads, pack} ----
    const int cpl = lane >> 2;          // 0..15 channel-pair sub-index
    const int pq  = lane & 3;           // 0..3  pixel-quad within wave tile
    const float* pb2 = pbase + prow0 + pq * 4;

#pragma unroll
    for (int half = 0; half < 2; ++half) {
        float4 va[4], vb[4];
#pragma unroll
        for (int p = 0; p < 4; ++p) {
            const int c0 = ((half * 4 + p) * 16 + cpl) * 2;
            va[p] = *(const float4*)(pb2 + (size_t)c0 * HW);
            vb[p] = *(const float4*)(pb2 + (size_t)(c0 + 1) * HW);
        }
#pragma unroll
        for (int p = 0; p < 4; ++p) {
            const int c0 = ((half * 4 + p) * 16 + cpl) * 2;
#pragma unroll
            for (int j = 0; j < 4; ++j) {
                const int row = prow0 + pq * 4 + j;
                const int col = c0 ^ (((row >> 3) & 3) << 3);
                *(unsigned*)(pt + row * PSTR + col) =
                    pkbf((&va[p].x)[j], (&vb[p].x)[j]);
            }
        }
    }
    // NO BARRIER: this wave reads only rows [prow0, prow0+16) that it wrote.

    // ---- MFMA: 8 och-tiles x K=256; W streamed with 1-deep kc prefetch ----
    const unsigned short* wrow = Wbf + (size_t)m * CIN + quad * 8;
    const int brow = prow0 + m;
    const int bswz = ((brow >> 3) & 3) << 3;

    float4v acc[8];
#pragma unroll
    for (int ot = 0; ot < 8; ++ot) acc[ot] = (float4v)0.f;

    short8 afC[8], afN[8];
#pragma unroll
    for (int ot = 0; ot < 8; ++ot)
        afC[ot] = *(const short8*)(wrow + (size_t)ot * 16 * CIN);

#pragma unroll
    for (int kc = 0; kc < 8; ++kc) {
        const int kn = (kc < 7) ? kc + 1 : 7;       // branchless tail
#pragma unroll
        for (int ot = 0; ot < 8; ++ot)
            afN[ot] = *(const short8*)(wrow + (size_t)ot * 16 * CIN + kn * 32);

        const short8 bf = *(const short8*)(pt + brow * PSTR
                                           + ((kc * 32 + quad * 8) ^ bswz));
#pragma unroll
        for (int ot = 0; ot < 8; ++ot)
            acc[ot] = __builtin_amdgcn_mfma_f32_16x16x32_bf16(afC[ot], bf, acc[ot], 0, 0, 0);
#pragma unroll
        for (int ot = 0; ot < 8; ++ot) afC[ot] = afN[ot];
    }

    // ---- in-wave l2norm: C col=lane&15=pixel, row=quad*4+reg=och ----
    float ss = 0.f;
#pragma unroll
    for (int ot = 0; ot < 8; ++ot)
#pragma unroll
        for (int r = 0; r < 4; ++r)
            ss = fmaf(acc[ot][r], acc[ot][r], ss);
    ss += __shfl_xor(ss, 16, 64);
    ss += __shfl_xor(ss, 32, 64);
    const float inv = 1.f / fmaxf(sqrtf(ss), 1e-12f);

    // ---- store bf16 pixel-major ----
#pragma unroll
    for (int ot = 0; ot < 8; ++ot) {
        uint2 st;
        st.x = pkbf(acc[ot][0] * inv, acc[ot][1] * inv);
        st.y = pkbf(acc[ot][2] * inv, acc[ot][3] * inv);
        *(uint2*)(outp + (size_t)(pgb + prow0 + m) * CMID + ot * 16 + quad * 4) = st;
    }
}

// ---------------------------------------------------------------------------
// Kernel 2: correlation via MFMA band-GEMM + Wv + geometry + softmax.
// EXACT R8 corr (best measured): staged phase A (10-deep issue-early/
// write-late; R7 proved staged > L2-direct by 5.2us), hoisted geometry,
// XCD-chunked bijective swizzle, hoisted A-frags + dual accumulators in
// phase B, transposed in-wave softmax, 2 barriers.
// __launch_bounds__(256,3): LDS-limited 3 blocks/CU.
// ---------------------------------------------------------------------------
constexpr int TILE = 16;
constexpr int COLS = TILE + 6;      // 22
constexpr int NV   = KS * COLS;     // 154 staged pixel-vectors
constexpr int KSTR = 136;           // shorts per vector in LDS (272 B)

__global__ __launch_bounds__(256, 3) void corr_kernel(
    const unsigned short* __restrict__ q_ws, const unsigned short* __restrict__ k_ws,
    const float* __restrict__ P_cur, const float* __restrict__ P_rnd,
    const float* __restrict__ wvp, const float* __restrict__ bv,
    const float* __restrict__ gamma_p, float* __restrict__ out)
{
    __shared__ unsigned short kt[NV * KSTR];                 // 41,888 B
    __shared__ alignas(16) unsigned short qt[TILE * KSTR];   //  4,352 B (ls overlay)
    __shared__ float cs[TILE][52];                           //  3,328 B corr vectors

    const int tid  = threadIdx.x;
    const int lane = tid & 63;
    const int wv   = __builtin_amdgcn_readfirstlane(tid >> 6);

    // ---- XCD-chunked bijective swizzle: fid -> contiguous 196-block chunk --
    const int fid = (blockIdx.z * H + blockIdx.y) * (W / TILE) + blockIdx.x;
    const int swz = (fid & 7) * 196 + (fid >> 3);
    const int b   = swz / (H * (W / TILE));
    const int rem = swz % (H * (W / TILE));
    const int h   = rem / (W / TILE);
    const int w0  = (rem % (W / TILE)) * TILE;

    // ---- phase A: ISSUE all staging loads into registers first ----
    const int sub  = tid & 15;
    const int vgrp = tid >> 4;          // 0..15
    uint4 stv[10];
#pragma unroll
    for (int pass = 0; pass < 10; ++pass) {
        const int vi = pass * 16 + vgrp;
        uint4 v = make_uint4(0, 0, 0, 0);
        if (vi < NV) {
            const int rr = vi / COLS;
            const int cc = vi % COLS;
            const int hh = h + rr - RAD;
            const int ww = w0 + cc - RAD;
            if (hh >= 0 && hh < H && ww >= 0 && ww < W)
                v = *(const uint4*)(k_ws + (size_t)(b * HW + hh * W + ww) * CMID + sub * 8);
        }
        stv[pass] = v;
    }
    const uint4 qv = *(const uint4*)(q_ws + (size_t)(b * HW + h * W + w0 + vgrp) * CMID + sub * 8);

    // ---- per-lane constants + HOISTED GEOMETRY (overlap staging loads) ----
    const int  ld    = (lane < DD) ? lane : 0;
    const bool valid = (lane < DD);
    float4 wq4[13];
#pragma unroll
    for (int j = 0; j < 13; ++j)
        wq4[j] = *(const float4*)(wvp + ld * 52 + j * 4);
    const float bvv   = bv[ld];
    const float gamma = gamma_p[0];

    const int dy = ld / KS - RAD;
    const int dx = ld % KS - RAD;
    float geo[4];
#pragma unroll
    for (int i = 0; i < 4; ++i) {
        const int pl = wv * 4 + i;      // pixel local 0..15
        const int hn = h + dy, wn = w0 + pl + dx;
        const bool inb = valid && hn >= 0 && hn < H && wn >= 0 && wn < W;
        const float* pc = P_cur + (size_t)b * 3 * HW + (h * W + w0 + pl);
        const float cx = pc[0], cy = pc[HW], cz = pc[2 * HW];
        float rx = 0.f, ry = 0.f, rz = 0.f;
        if (inb) {
            const float* pr = P_rnd + (size_t)b * 3 * HW + (hn * W + wn);
            rx = pr[0]; ry = pr[HW]; rz = pr[2 * HW];
        }
        const float dpx = cx - rx, dpy = cy - ry, dpz = cz - rz;
        const float dist = sqrtf(fmaxf(dpx * dpx + dpy * dpy + dpz * dpz, 1e-12f));
        geo[i] = gamma * (-dist - 0.5f * fabsf(dpz));
    }

    // ---- phase A: LDS writes (waits only on the k/q loads) ----
#pragma unroll
    for (int pass = 0; pass < 10; ++pass) {
        const int vi = pass * 16 + vgrp;
        if (vi < NV)
            *(uint4*)(kt + vi * KSTR + sub * 8) = stv[pass];
    }
    *(uint4*)(qt + vgrp * KSTR + sub * 8) = qv;

    __syncthreads();

    // zero the cs padding (cols 49..51) so phase C1's 0*pad stays 0
    if (tid < TILE * 3)
        cs[tid / 3][49 + tid % 3] = 0.f;

    // ---- phase B: MFMA band-GEMM (A-frags hoisted; dual accumulators) ----
    const int m = lane & 15, quad = lane >> 4;
    short8 aqf[4];
#pragma unroll
    for (int kc = 0; kc < 4; ++kc)
        aqf[kc] = *(const short8*)(qt + m * KSTR + kc * 32 + quad * 8);

    for (int g = wv; g < 14; g += 4) {
        const int r  = g >> 1;
        const int nt = g & 1;
        const int vi = min(r * COLS + nt * 16 + m, NV - 1);  // clamp OOB cols
        const short8 b0 = *(const short8*)(kt + vi * KSTR + 0 * 32 + quad * 8);
        const short8 b1 = *(const short8*)(kt + vi * KSTR + 1 * 32 + quad * 8);
        const short8 b2 = *(const short8*)(kt + vi * KSTR + 2 * 32 + quad * 8);
        const short8 b3 = *(const short8*)(kt + vi * KSTR + 3 * 32 + quad * 8);
        float4v a0 = (float4v)0.f, a1 = (float4v)0.f;
        a0 = __builtin_amdgcn_mfma_f32_16x16x32_bf16(aqf[0], b0, a0, 0, 0, 0);
        a1 = __builtin_amdgcn_mfma_f32_16x16x32_bf16(aqf[1], b1, a1, 0, 0, 0);
        a0 = __builtin_amdgcn_mfma_f32_16x16x32_bf16(aqf[2], b2, a0, 0, 0, 0);
        a1 = __builtin_amdgcn_mfma_f32_16x16x32_bf16(aqf[3], b3, a1, 0, 0, 0);
#pragma unroll
        for (int r4 = 0; r4 < 4; ++r4) a0[r4] += a1[r4];
        // band extract: D row = pixel = quad*4+reg, col cc = nt*16 + m
#pragma unroll
        for (int reg = 0; reg < 4; ++reg) {
            const int p   = quad * 4 + reg;
            const int off = nt * 16 + m - p;     // dx + RAD
            if (off >= 0 && off <= 6)
                cs[p][r * 7 + off] = a0[reg];
        }
    }
    __syncthreads();
    // qt is dead from here on -> overlay ls (16 rows x 64 f32 = 4,096 B)
    float* lsf = reinterpret_cast<float*>(qt);

    // ---- phase C1: pure dot + add (lane = d); write logit rows to ls ----
#pragma unroll
    for (int i = 0; i < 4; ++i) {
        const int pl = wv * 4 + i;      // pixel local 0..15
        float logit = -INFINITY;
        if (valid) {
            float va0 = bvv, va1 = 0.f;     // dual independent FMA chains
#pragma unroll
            for (int e4 = 0; e4 < 13; ++e4) {
                const float4 c4 = *(const float4*)&cs[pl][e4 * 4];
                const float4 w4 = wq4[e4];
                if (e4 & 1) {
                    va1 = fmaf(w4.x, c4.x, va1);
                    va1 = fmaf(w4.y, c4.y, va1);
                    va1 = fmaf(w4.z, c4.z, va1);
                    va1 = fmaf(w4.w, c4.w, va1);
                } else {
                    va0 = fmaf(w4.x, c4.x, va0);
                    va0 = fmaf(w4.y, c4.y, va0);
                    va0 = fmaf(w4.z, c4.z, va0);
                    va0 = fmaf(w4.w, c4.w, va0);
                }
            }
            logit = (va0 + va1) + geo[i];
        }
        lsf[pl * 64 + lane] = logit;    // lanes 49..63 store -inf
    }

    // ---- phase C2: transposed in-wave softmax (lane = pixel x col-quad) ----
    // Same-wave LDS write->read: compiler-ordered via lgkmcnt, no barrier.
    {
        const int pli = lane >> 4;      // 0..3 within wave
        const int dq  = lane & 15;      // column quad (cols dq*4 .. dq*4+3)
        const int pl  = wv * 4 + pli;

        const float4 v = ((const float4*)lsf)[pl * 16 + dq];

        float m4 = fmaxf(fmaxf(v.x, v.y), fmaxf(v.z, v.w));
#pragma unroll
        for (int s = 1; s < 16; s <<= 1)
            m4 = fmaxf(m4, __shfl_xor(m4, s, 64));

        const float e0 = __expf(v.x - m4);
        const float e1 = __expf(v.y - m4);
        const float e2 = __expf(v.z - m4);
        const float e3 = __expf(v.w - m4);
        float Z = (e0 + e1) + (e2 + e3);

        // dx = col%7-3, dy = col/7-3  (cols >= 49 have e == 0, values moot)
        const int c0i = dq * 4;
        float dus = 0.f, dvs = 0.f;
        {
            const float ex[4] = { e0, e1, e2, e3 };
#pragma unroll
            for (int j = 0; j < 4; ++j) {
                const int col = c0i + j;
                dus = fmaf(ex[j], (float)(col % KS - RAD), dus);
                dvs = fmaf(ex[j], (float)(col / KS - RAD), dvs);
            }
        }
#pragma unroll
        for (int s = 1; s < 16; s <<= 1) {
            Z   += __shfl_xor(Z,   s, 64);
            dus += __shfl_xor(dus, s, 64);
            dvs += __shfl_xor(dvs, s, 64);
        }

        if (dq == 0) {
            const int pg = b * HW + h * W + w0 + pl;
            const float invZ = 1.f / Z;
            out[pg]            = dus * invZ;
            out[NPIX + pg]     = dvs * invZ;
            out[2 * NPIX + pg] = invZ;       // conf = max w = exp(lmax-lmax)/Z
        }
    }
}

// ---------------------------------------------------------------------------
extern "C" void kernel_launch(void* const* d_in, const int* in_sizes, int n_in,
                              void* d_out, int out_size, void* d_ws, size_t ws_size,
                              hipStream_t stream)
{
    const float* phi_cur = (const float*)d_in[0];
    const float* phi_rnd = (const float*)d_in[1];
    const float* P_cur   = (const float*)d_in[2];
    const float* P_rnd   = (const float*)d_in[3];
    const float* Wq      = (const float*)d_in[4];
    const float* Wk      = (const float*)d_in[5];
    const float* Wv      = (const float*)d_in[6];
    const float* bv      = (const float*)d_in[7];
    const float* gm      = (const float*)d_in[8];
    float* out = (float*)d_out;

    unsigned short* ws   = (unsigned short*)d_ws;
    unsigned short* q_ws = ws;                                  // NPIX*CMID bf16
    unsigned short* k_ws = q_ws + (size_t)NPIX * CMID;          // NPIX*CMID bf16
    unsigned short* wqb  = k_ws + (size_t)NPIX * CMID;          // CMID*CIN bf16
    unsigned short* wkb  = wqb + (size_t)CMID * CIN;
    float*          wvp  = (float*)(wkb + (size_t)CMID * CIN);  // 49x52 f32 (16B-aligned)

    prep<<<dim3(65), 256, 0, stream>>>(Wq, Wk, Wv, wqb, wkb, wvp);

    proj_mfma<<<dim3(NPIX / 64, 2), 256, 0, stream>>>(
        phi_cur, phi_rnd, wqb, wkb, q_ws, k_ws);

    corr_kernel<<<dim3(W / TILE, H, B), 256, 0, stream>>>(
        q_ws, k_ws, P_cur, P_rnd, wvp, bv, gm, out);
}

// Round 12
// 131.409 us; speedup vs baseline: 1.1507x; 1.1507x over previous
//
#include <hip/hip_runtime.h>
#include <hip/hip_bf16.h>
#include <math.h>

// Problem constants (B, Cin, Cmid, H, W) = (2, 256, 128, 112, 112), R=3
constexpr int B    = 2;
constexpr int CIN  = 256;
constexpr int CMID = 128;
constexpr int H    = 112;
constexpr int W    = 112;
constexpr int HW   = H * W;        // 12544
constexpr int NPIX = B * HW;       // 25088
constexpr int RAD  = 3;
constexpr int KS   = 7;
constexpr int DD   = 49;

typedef __attribute__((ext_vector_type(8))) short  short8;   // 8 bf16 (4 VGPR)
typedef __attribute__((ext_vector_type(4))) float  float4v;  // MFMA C/D

// RNE fp32-pair -> packed bf16x2 via v_cvt_pk_bf16_f32 (compiler-lowered)
__device__ __forceinline__ unsigned pkbf(float a, float b) {
    __hip_bfloat162 h = __float22bfloat162_rn(make_float2(a, b));
    union { __hip_bfloat162 h2; unsigned u; } c;
    c.h2 = h;
    return c.u;
}

// ---------------------------------------------------------------------------
// Kernel 0 (prep, tiny): Wq/Wk f32 -> bf16; Wv f32 -> padded f32 [49][52].
// Kept SEPARATE (R6 fold regressed: VGPR spill past the 128 cap in proj).
// ---------------------------------------------------------------------------
__global__ __launch_bounds__(256) void prep(
    const float* __restrict__ Wq, const float* __restrict__ Wk,
    const float* __restrict__ Wv,
    unsigned short* __restrict__ wqb, unsigned short* __restrict__ wkb,
    float* __restrict__ wvp)
{
    if (blockIdx.x < 64) {
        const int i  = blockIdx.x * 256 + threadIdx.x;   // float4 index
        const int n4 = (CMID * CIN) / 4;                 // 8192 per matrix
        const float4 v = (i < n4) ? ((const float4*)Wq)[i] : ((const float4*)Wk)[i - n4];
        uint2 r;
        r.x = pkbf(v.x, v.y);
        r.y = pkbf(v.z, v.w);
        if (i < n4) ((uint2*)wqb)[i] = r;
        else        ((uint2*)wkb)[i - n4] = r;
    } else {
        for (int idx = threadIdx.x; idx < DD * 52; idx += 256) {
            const int r = idx / 52, c = idx % 52;
            wvp[idx] = (c < DD) ? Wv[r * DD + c] : 0.f;
        }
    }
}

// ---------------------------------------------------------------------------
// Kernel 1: q = l2norm(Wq @ phi_cur), k = l2norm(Wk @ phi_rnd)  via bf16 MFMA.
// EXACT R8 kernel (best measured, 130.6; reproduced 132.4 byte-identical).
// Structural constraint (R11 falsified the alternative): pixel-split needs
// all of W per wave (64 KB, can't live in registers); och-split needs the
// block-cooperative staging barrier.  R8 = optimum of that tradeoff:
//  (1) A-frags (16 x b128, L2-hot bf16 W, 32 VGPR) issued FIRST -- the
//      compiler cannot hoist loads across __syncthreads; pre-barrier issue
//      hides their latency under staging + barrier.  K-loop then has ZERO
//      global loads: pure {4 ds_read_b128 + 8 MFMA} per kc.
//  (2) staging split issue-early/write-late (T14): 2 batches of 8 float4
//      loads in flight, then pack/write.  (R9 single-batch: noise-level.)
// LDS: pixel-major bf16, PSTR=264, col XOR-swizzle ((pix>>3)&3)<<3
// (staging b32 writes 2-way = free, frag b128 reads at structural optimum).
// __launch_bounds__(256,4): 4 blocks/CU, all 784 co-resident.
// ---------------------------------------------------------------------------
constexpr int PSTR = 264;           // shorts per pixel row in pt

__global__ __launch_bounds__(256, 4) void proj_mfma(
    const float* __restrict__ phi_cur, const float* __restrict__ phi_rnd,
    const unsigned short* __restrict__ wq_bf, const unsigned short* __restrict__ wk_bf,
    unsigned short* __restrict__ q_ws, unsigned short* __restrict__ k_ws)
{
    __shared__ unsigned short pt[64 * PSTR];  // 33,792 B  pixel-major bf16
    __shared__ float red[4][64];

    const int tid  = threadIdx.x;
    const int lane = tid & 63;
    const int wv   = __builtin_amdgcn_readfirstlane(tid >> 6);
    const int t    = blockIdx.y;                    // 0 -> q, 1 -> k

    const float* __restrict__ phi          = t ? phi_rnd : phi_cur;
    const unsigned short* __restrict__ Wbf = t ? wk_bf : wq_bf;
    unsigned short* __restrict__ outp      = t ? k_ws : q_ws;

    const int pgb = blockIdx.x * 64;                // 64-aligned, no b crossing
    const int b   = pgb / HW;
    const int pim = pgb % HW;
    const float* pbase = phi + (size_t)b * CIN * HW + pim;

    const int m = lane & 15, quad = lane >> 4;

    // ---- (1) A-frag preload: issue 16 b128 loads NOW; consumed post-barrier
    short8 af[2][8];
#pragma unroll
    for (int ot = 0; ot < 2; ++ot)
#pragma unroll
        for (int kc = 0; kc < 8; ++kc)
            af[ot][kc] = *(const short8*)(Wbf +
                (size_t)(wv * 32 + ot * 16 + m) * CIN + kc * 32 + quad * 8);

    // ---- (2) stage phi tile: 2 batches x {issue 8 f4 loads, pack+write} ----
#pragma unroll
    for (int half = 0; half < 2; ++half) {
        float4 va[4], vb[4];
#pragma unroll
        for (int p = 0; p < 4; ++p) {
            const int idx = (half * 4 + p) * 256 + tid;
            const int cp  = idx >> 4;          // channel pair 0..127
            const int pq  = idx & 15;          // pixel quad  0..15
            const int c0  = cp * 2;
            va[p] = *(const float4*)(pbase + (size_t)c0 * HW + pq * 4);
            vb[p] = *(const float4*)(pbase + (size_t)(c0 + 1) * HW + pq * 4);
        }
#pragma unroll
        for (int p = 0; p < 4; ++p) {
            const int idx = (half * 4 + p) * 256 + tid;
            const int cp  = idx >> 4;
            const int pq  = idx & 15;
            const int c0  = cp * 2;
            const int swz = ((pq >> 1) & 3) << 3;        // == ((pix>>3)&3)<<3
            const int col = c0 ^ swz;
            *(unsigned*)(pt + (pq * 4 + 0) * PSTR + col) = pkbf(va[p].x, vb[p].x);
            *(unsigned*)(pt + (pq * 4 + 1) * PSTR + col) = pkbf(va[p].y, vb[p].y);
            *(unsigned*)(pt + (pq * 4 + 2) * PSTR + col) = pkbf(va[p].z, vb[p].z);
            *(unsigned*)(pt + (pq * 4 + 3) * PSTR + col) = pkbf(va[p].w, vb[p].w);
        }
    }

    __syncthreads();

    // ---- MFMA: 2 out-tiles x 4 pixel-tiles x K=256 (af already resident) ----
    float4v acc[2][4];
#pragma unroll
    for (int ot = 0; ot < 2; ++ot)
#pragma unroll
        for (int nt = 0; nt < 4; ++nt) acc[ot][nt] = (float4v)0.f;

#pragma unroll
    for (int kc = 0; kc < 8; ++kc) {
        short8 bfr[4];
#pragma unroll
        for (int nt = 0; nt < 4; ++nt) {
            const int row = nt * 16 + m;
            const int col = (kc * 32 + quad * 8) ^ (((row >> 3) & 3) << 3);
            bfr[nt] = *(const short8*)(pt + row * PSTR + col);
        }
#pragma unroll
        for (int nt = 0; nt < 4; ++nt) {
            acc[0][nt] = __builtin_amdgcn_mfma_f32_16x16x32_bf16(af[0][kc], bfr[nt], acc[0][nt], 0, 0, 0);
            acc[1][nt] = __builtin_amdgcn_mfma_f32_16x16x32_bf16(af[1][kc], bfr[nt], acc[1][nt], 0, 0, 0);
        }
    }

    // ---- per-pixel L2 norm: C layout col=lane&15=pixel, row=quad*4+reg=och
#pragma unroll
    for (int nt = 0; nt < 4; ++nt) {
        float ss = 0.f;
#pragma unroll
        for (int ot = 0; ot < 2; ++ot)
#pragma unroll
            for (int r = 0; r < 4; ++r)
                ss = fmaf(acc[ot][nt][r], acc[ot][nt][r], ss);
        ss += __shfl_xor(ss, 16, 64);
        ss += __shfl_xor(ss, 32, 64);
        if (quad == 0) red[wv][nt * 16 + m] = ss;
    }
    __syncthreads();

    float inv[4];
#pragma unroll
    for (int nt = 0; nt < 4; ++nt) {
        const int px = nt * 16 + m;
        const float tot = red[0][px] + red[1][px] + red[2][px] + red[3][px];
        inv[nt] = 1.f / fmaxf(sqrtf(tot), 1e-12f);
    }

    // ---- store bf16 pixel-major ----
#pragma unroll
    for (int nt = 0; nt < 4; ++nt)
#pragma unroll
        for (int ot = 0; ot < 2; ++ot) {
            uint2 st;
            st.x = pkbf(acc[ot][nt][0] * inv[nt], acc[ot][nt][1] * inv[nt]);
            st.y = pkbf(acc[ot][nt][2] * inv[nt], acc[ot][nt][3] * inv[nt]);
            *(uint2*)(outp + (size_t)(pgb + nt * 16 + m) * CMID
                      + wv * 32 + ot * 16 + quad * 4) = st;
        }
}

// ---------------------------------------------------------------------------
// Kernel 2: correlation via MFMA band-GEMM + Wv + geometry + softmax.
// EXACT R8 corr (best measured): staged phase A (10-deep issue-early/
// write-late; R7 proved staged > L2-direct by 5.2us), hoisted geometry,
// XCD-chunked bijective swizzle, hoisted A-frags + dual accumulators in
// phase B, transposed in-wave softmax, 2 barriers.
// __launch_bounds__(256,3): LDS-limited 3 blocks/CU.
// ---------------------------------------------------------------------------
constexpr int TILE = 16;
constexpr int COLS = TILE + 6;      // 22
constexpr int NV   = KS * COLS;     // 154 staged pixel-vectors
constexpr int KSTR = 136;           // shorts per vector in LDS (272 B)

__global__ __launch_bounds__(256, 3) void corr_kernel(
    const unsigned short* __restrict__ q_ws, const unsigned short* __restrict__ k_ws,
    const float* __restrict__ P_cur, const float* __restrict__ P_rnd,
    const float* __restrict__ wvp, const float* __restrict__ bv,
    const float* __restrict__ gamma_p, float* __restrict__ out)
{
    __shared__ unsigned short kt[NV * KSTR];                 // 41,888 B
    __shared__ alignas(16) unsigned short qt[TILE * KSTR];   //  4,352 B (ls overlay)
    __shared__ float cs[TILE][52];                           //  3,328 B corr vectors

    const int tid  = threadIdx.x;
    const int lane = tid & 63;
    const int wv   = __builtin_amdgcn_readfirstlane(tid >> 6);

    // ---- XCD-chunked bijective swizzle: fid -> contiguous 196-block chunk --
    const int fid = (blockIdx.z * H + blockIdx.y) * (W / TILE) + blockIdx.x;
    const int swz = (fid & 7) * 196 + (fid >> 3);
    const int b   = swz / (H * (W / TILE));
    const int rem = swz % (H * (W / TILE));
    const int h   = rem / (W / TILE);
    const int w0  = (rem % (W / TILE)) * TILE;

    // ---- phase A: ISSUE all staging loads into registers first ----
    const int sub  = tid & 15;
    const int vgrp = tid >> 4;          // 0..15
    uint4 stv[10];
#pragma unroll
    for (int pass = 0; pass < 10; ++pass) {
        const int vi = pass * 16 + vgrp;
        uint4 v = make_uint4(0, 0, 0, 0);
        if (vi < NV) {
            const int rr = vi / COLS;
            const int cc = vi % COLS;
            const int hh = h + rr - RAD;
            const int ww = w0 + cc - RAD;
            if (hh >= 0 && hh < H && ww >= 0 && ww < W)
                v = *(const uint4*)(k_ws + (size_t)(b * HW + hh * W + ww) * CMID + sub * 8);
        }
        stv[pass] = v;
    }
    const uint4 qv = *(const uint4*)(q_ws + (size_t)(b * HW + h * W + w0 + vgrp) * CMID + sub * 8);

    // ---- per-lane constants + HOISTED GEOMETRY (overlap staging loads) ----
    const int  ld    = (lane < DD) ? lane : 0;
    const bool valid = (lane < DD);
    float4 wq4[13];
#pragma unroll
    for (int j = 0; j < 13; ++j)
        wq4[j] = *(const float4*)(wvp + ld * 52 + j * 4);
    const float bvv   = bv[ld];
    const float gamma = gamma_p[0];

    const int dy = ld / KS - RAD;
    const int dx = ld % KS - RAD;
    float geo[4];
#pragma unroll
    for (int i = 0; i < 4; ++i) {
        const int pl = wv * 4 + i;      // pixel local 0..15
        const int hn = h + dy, wn = w0 + pl + dx;
        const bool inb = valid && hn >= 0 && hn < H && wn >= 0 && wn < W;
        const float* pc = P_cur + (size_t)b * 3 * HW + (h * W + w0 + pl);
        const float cx = pc[0], cy = pc[HW], cz = pc[2 * HW];
        float rx = 0.f, ry = 0.f, rz = 0.f;
        if (inb) {
            const float* pr = P_rnd + (size_t)b * 3 * HW + (hn * W + wn);
            rx = pr[0]; ry = pr[HW]; rz = pr[2 * HW];
        }
        const float dpx = cx - rx, dpy = cy - ry, dpz = cz - rz;
        const float dist = sqrtf(fmaxf(dpx * dpx + dpy * dpy + dpz * dpz, 1e-12f));
        geo[i] = gamma * (-dist - 0.5f * fabsf(dpz));
    }

    // ---- phase A: LDS writes (waits only on the k/q loads) ----
#pragma unroll
    for (int pass = 0; pass < 10; ++pass) {
        const int vi = pass * 16 + vgrp;
        if (vi < NV)
            *(uint4*)(kt + vi * KSTR + sub * 8) = stv[pass];
    }
    *(uint4*)(qt + vgrp * KSTR + sub * 8) = qv;

    __syncthreads();

    // zero the cs padding (cols 49..51) so phase C1's 0*pad stays 0
    if (tid < TILE * 3)
        cs[tid / 3][49 + tid % 3] = 0.f;

    // ---- phase B: MFMA band-GEMM (A-frags hoisted; dual accumulators) ----
    const int m = lane & 15, quad = lane >> 4;
    short8 aqf[4];
#pragma unroll
    for (int kc = 0; kc < 4; ++kc)
        aqf[kc] = *(const short8*)(qt + m * KSTR + kc * 32 + quad * 8);

    for (int g = wv; g < 14; g += 4) {
        const int r  = g >> 1;
        const int nt = g & 1;
        const int vi = min(r * COLS + nt * 16 + m, NV - 1);  // clamp OOB cols
        const short8 b0 = *(const short8*)(kt + vi * KSTR + 0 * 32 + quad * 8);
        const short8 b1 = *(const short8*)(kt + vi * KSTR + 1 * 32 + quad * 8);
        const short8 b2 = *(const short8*)(kt + vi * KSTR + 2 * 32 + quad * 8);
        const short8 b3 = *(const short8*)(kt + vi * KSTR + 3 * 32 + quad * 8);
        float4v a0 = (float4v)0.f, a1 = (float4v)0.f;
        a0 = __builtin_amdgcn_mfma_f32_16x16x32_bf16(aqf[0], b0, a0, 0, 0, 0);
        a1 = __builtin_amdgcn_mfma_f32_16x16x32_bf16(aqf[1], b1, a1, 0, 0, 0);
        a0 = __builtin_amdgcn_mfma_f32_16x16x32_bf16(aqf[2], b2, a0, 0, 0, 0);
        a1 = __builtin_amdgcn_mfma_f32_16x16x32_bf16(aqf[3], b3, a1, 0, 0, 0);
#pragma unroll
        for (int r4 = 0; r4 < 4; ++r4) a0[r4] += a1[r4];
        // band extract: D row = pixel = quad*4+reg, col cc = nt*16 + m
#pragma unroll
        for (int reg = 0; reg < 4; ++reg) {
            const int p   = quad * 4 + reg;
            const int off = nt * 16 + m - p;     // dx + RAD
            if (off >= 0 && off <= 6)
                cs[p][r * 7 + off] = a0[reg];
        }
    }
    __syncthreads();
    // qt is dead from here on -> overlay ls (16 rows x 64 f32 = 4,096 B)
    float* lsf = reinterpret_cast<float*>(qt);

    // ---- phase C1: pure dot + add (lane = d); write logit rows to ls ----
#pragma unroll
    for (int i = 0; i < 4; ++i) {
        const int pl = wv * 4 + i;      // pixel local 0..15
        float logit = -INFINITY;
        if (valid) {
            float va0 = bvv, va1 = 0.f;     // dual independent FMA chains
#pragma unroll
            for (int e4 = 0; e4 < 13; ++e4) {
                const float4 c4 = *(const float4*)&cs[pl][e4 * 4];
                const float4 w4 = wq4[e4];
                if (e4 & 1) {
                    va1 = fmaf(w4.x, c4.x, va1);
                    va1 = fmaf(w4.y, c4.y, va1);
                    va1 = fmaf(w4.z, c4.z, va1);
                    va1 = fmaf(w4.w, c4.w, va1);
                } else {
                    va0 = fmaf(w4.x, c4.x, va0);
                    va0 = fmaf(w4.y, c4.y, va0);
                    va0 = fmaf(w4.z, c4.z, va0);
                    va0 = fmaf(w4.w, c4.w, va0);
                }
            }
            logit = (va0 + va1) + geo[i];
        }
        lsf[pl * 64 + lane] = logit;    // lanes 49..63 store -inf
    }

    // ---- phase C2: transposed in-wave softmax (lane = pixel x col-quad) ----
    // Same-wave LDS write->read: compiler-ordered via lgkmcnt, no barrier.
    {
        const int pli = lane >> 4;      // 0..3 within wave
        const int dq  = lane & 15;      // column quad (cols dq*4 .. dq*4+3)
        const int pl  = wv * 4 + pli;

        const float4 v = ((const float4*)lsf)[pl * 16 + dq];

        float m4 = fmaxf(fmaxf(v.x, v.y), fmaxf(v.z, v.w));
#pragma unroll
        for (int s = 1; s < 16; s <<= 1)
            m4 = fmaxf(m4, __shfl_xor(m4, s, 64));

        const float e0 = __expf(v.x - m4);
        const float e1 = __expf(v.y - m4);
        const float e2 = __expf(v.z - m4);
        const float e3 = __expf(v.w - m4);
        float Z = (e0 + e1) + (e2 + e3);

        // dx = col%7-3, dy = col/7-3  (cols >= 49 have e == 0, values moot)
        const int c0i = dq * 4;
        float dus = 0.f, dvs = 0.f;
        {
            const float ex[4] = { e0, e1, e2, e3 };
#pragma unroll
            for (int j = 0; j < 4; ++j) {
                const int col = c0i + j;
                dus = fmaf(ex[j], (float)(col % KS - RAD), dus);
                dvs = fmaf(ex[j], (float)(col / KS - RAD), dvs);
            }
        }
#pragma unroll
        for (int s = 1; s < 16; s <<= 1) {
            Z   += __shfl_xor(Z,   s, 64);
            dus += __shfl_xor(dus, s, 64);
            dvs += __shfl_xor(dvs, s, 64);
        }

        if (dq == 0) {
            const int pg = b * HW + h * W + w0 + pl;
            const float invZ = 1.f / Z;
            out[pg]            = dus * invZ;
            out[NPIX + pg]     = dvs * invZ;
            out[2 * NPIX + pg] = invZ;       // conf = max w = exp(lmax-lmax)/Z
        }
    }
}

// ---------------------------------------------------------------------------
extern "C" void kernel_launch(void* const* d_in, const int* in_sizes, int n_in,
                              void* d_out, int out_size, void* d_ws, size_t ws_size,
                              hipStream_t stream)
{
    const float* phi_cur = (const float*)d_in[0];
    const float* phi_rnd = (const float*)d_in[1];
    const float* P_cur   = (const float*)d_in[2];
    const float* P_rnd   = (const float*)d_in[3];
    const float* Wq      = (const float*)d_in[4];
    const float* Wk      = (const float*)d_in[5];
    const float* Wv      = (const float*)d_in[6];
    const float* bv      = (const float*)d_in[7];
    const float* gm      = (const float*)d_in[8];
    float* out = (float*)d_out;

    unsigned short* ws   = (unsigned short*)d_ws;
    unsigned short* q_ws = ws;                                  // NPIX*CMID bf16
    unsigned short* k_ws = q_ws + (size_t)NPIX * CMID;          // NPIX*CMID bf16
    unsigned short* wqb  = k_ws + (size_t)NPIX * CMID;          // CMID*CIN bf16
    unsigned short* wkb  = wqb + (size_t)CMID * CIN;
    float*          wvp  = (float*)(wkb + (size_t)CMID * CIN);  // 49x52 f32 (16B-aligned)

    prep<<<dim3(65), 256, 0, stream>>>(Wq, Wk, Wv, wqb, wkb, wvp);

    proj_mfma<<<dim3(NPIX / 64, 2), 256, 0, stream>>>(
        phi_cur, phi_rnd, wqb, wkb, q_ws, k_ws);

    corr_kernel<<<dim3(W / TILE, H, B), 256, 0, stream>>>(
        q_ws, k_ws, P_cur, P_rnd, wvp, bv, gm, out);
}